// Round 12
// baseline (97.729 us; speedup 1.0000x reference)
//
#include <hip/hip_runtime.h>
#include <hip/hip_bf16.h>
#include <math.h>

// ---- problem constants ----
#define NCAMS 6
#define BH_ 100
#define BW_ 100
#define CDIM 256
#define NQ_ 4000           // HG*WG = 100*40
#define HF_ 48
#define WF_ 80
#define HEADS_ 8
#define PTS_ 8
#define HD_ 32
#define HWV (HF_*WF_)      // 3840
#define M1_ (NCAMS*HWV)    // 23040
#define M2_ (NCAMS*NQ_)    // 24000
#define NOUT_ 10000        // BH*BW
#define VHSHIFT 5898240    // elements in one vh copy (48 slices x 122880)

#define SA 264             // padded LDS tile row stride in bf16 elems
#define SOFF 132           // padded off row stride (floats)
#define SATT 68            // padded att row stride (floats)

typedef __bf16 bf16_t;
typedef __bf16 bf16x8 __attribute__((ext_vector_type(8)));
typedef __bf16 bf16x4 __attribute__((ext_vector_type(4)));
typedef float  f32x4  __attribute__((ext_vector_type(4)));

static __device__ __forceinline__ f32x4 mfma16(bf16x8 a, bf16x8 b, f32x4 c) {
    return __builtin_amdgcn_mfma_f32_16x16x32_bf16(a, b, c, 0, 0, 0);
}

// K0: bf16 transposed weights + qsum = (bf16)(query + query_pos).
__global__ __launch_bounds__(256) void k0_prep(const float* __restrict__ Wv,
                                               const float* __restrict__ Woff,
                                               const float* __restrict__ Watt,
                                               const float* __restrict__ Wout,
                                               const float* __restrict__ query,
                                               const float* __restrict__ qpos,
                                               bf16_t* __restrict__ WvT,
                                               bf16_t* __restrict__ WcombT,
                                               bf16_t* __restrict__ WoutT,
                                               bf16_t* __restrict__ qsum) {
    int b = blockIdx.x, k = threadIdx.x;
    if (b < 256) {
        WvT[b * 256 + k] = (bf16_t)Wv[k * 256 + b];
    } else if (b < 448) {
        int n = b - 256;
        float v = (n < 128) ? Woff[k * 128 + n] : Watt[k * 64 + (n - 128)];
        WcombT[n * 256 + k] = (bf16_t)v;
    } else if (b < 704) {
        int n = b - 448;
        WoutT[n * 256 + k] = (bf16_t)Wout[k * 256 + n];
    } else {
        int row0 = (b - 704) * 4;                 // 4 rows per block
        int r = k >> 6, c4 = k & 63;
        int i = (row0 + r) * 64 + c4;             // float4 index
        float4 a = ((const float4*)query)[i];
        float4 p = ((const float4*)qpos)[i];
        bf16x4 pk;
        pk[0] = (bf16_t)(a.x + p.x); pk[1] = (bf16_t)(a.y + p.y);
        pk[2] = (bf16_t)(a.z + p.z); pk[3] = (bf16_t)(a.w + p.w);
        *(bf16x4*)(qsum + (size_t)i * 4) = pk;
    }
}

// K1: vh[cam][head][hw][hd] (bf16) = value @ Wv + bv. MFMA, 32x256 tile.
// Epilogue writes vhE and the shift-by-one-texel copy vhO (tail = texel-79 dup)
// so any x-corner pair is one 128B-aligned contiguous region.
__global__ __launch_bounds__(256) void k1_vproj(const float* __restrict__ value,
                                                const bf16_t* __restrict__ WvT,
                                                const float* __restrict__ bv,
                                                bf16_t* __restrict__ vh) {
    __shared__ __align__(16) bf16_t At[32 * SA];
    const int m0 = blockIdx.x * 32;
    const int cam = m0 / HWV;
    const int hw0 = m0 - cam * HWV;
    for (int idx = threadIdx.x; idx < 32 * 64; idx += 256) {
        int r = idx >> 6, c4 = idx & 63;
        float4 v = ((const float4*)value)[((hw0 + r) * NCAMS + cam) * 64 + c4];
        bf16x4 pk; pk[0] = (bf16_t)v.x; pk[1] = (bf16_t)v.y; pk[2] = (bf16_t)v.z; pk[3] = (bf16_t)v.w;
        *(bf16x4*)(At + r * SA + c4 * 4) = pk;
    }
    __syncthreads();
    const int lane = threadIdx.x & 63, w = threadIdx.x >> 6;
    const int lr = lane & 15, lk = lane >> 4;
    f32x4 acc[2][4] = {};
    const bf16_t* a0 = At + lr * SA + lk * 8;
    const bf16_t* b0 = WvT + (w * 64 + lr) * 256 + lk * 8;
#pragma unroll
    for (int ks = 0; ks < 8; ++ks) {
        bf16x8 af[2], bf_[4];
#pragma unroll
        for (int mm = 0; mm < 2; ++mm) af[mm] = *(const bf16x8*)(a0 + mm * 16 * SA + ks * 32);
#pragma unroll
        for (int n = 0; n < 4; ++n) bf_[n] = *(const bf16x8*)(b0 + n * 16 * 256 + ks * 32);
#pragma unroll
        for (int mm = 0; mm < 2; ++mm)
#pragma unroll
            for (int n = 0; n < 4; ++n)
                acc[mm][n] = mfma16(af[mm], bf_[n], acc[mm][n]);
    }
    __syncthreads();
#pragma unroll
    for (int n = 0; n < 4; ++n) {
        int col = w * 64 + n * 16 + lr;
        float bias = bv[col];
#pragma unroll
        for (int mm = 0; mm < 2; ++mm)
#pragma unroll
            for (int j = 0; j < 4; ++j)
                At[(mm * 16 + lk * 4 + j) * SA + col] = (bf16_t)(acc[mm][n][j] + bias);
    }
    __syncthreads();
    // stores: 32 rows x 32 octets -> vhE, plus shifted copy into vhO
    for (int idx = threadIdx.x; idx < 32 * 32; idx += 256) {
        int r = idx >> 5, g = idx & 31;
        int head = g >> 2, part = g & 3;
        bf16x8 v = *(const bf16x8*)(At + r * SA + g * 8);
        int hw = hw0 + r;
        int y = hw / WF_;
        int x = hw - y * WF_;
        size_t rowbase = ((size_t)(cam * HEADS_ + head) * HF_ + y) * (WF_ * HD_);
        int o = x * HD_ + part * 8;
        *(bf16x8*)(vh + rowbase + o) = v;                              // vhE
        if (o >= 32) *(bf16x8*)(vh + VHSHIFT + rowbase + o - 32) = v;  // vhO main
        if (x == WF_ - 1) *(bf16x8*)(vh + VHSHIFT + rowbase + o) = v;  // vhO tail dup
    }
}

// K23: fused offsets/attention GEMM + bilinear deformable sampling.
// Phase 2: 8-LANE UNITS — each unit's corner x-pair is ONE contiguous 128B
// access (8 lanes x 16B) from the parity-selected vh copy. Per point only 2
// load instructions (y0-pair, y1-pair): tests 128B-line TA coalescing.
// 4 passes of 32 units cover the 16 rows x 8 heads.
__global__ __launch_bounds__(256) void k23_offatt_sample(
        const bf16_t* __restrict__ qsum,
        const float* __restrict__ qgrid,
        const bf16_t* __restrict__ WcombT,
        const float* __restrict__ boff,
        const float* __restrict__ batt,
        const float* __restrict__ refp,
        const bf16_t* __restrict__ vh,
        bf16_t* __restrict__ out_attn) {
    __shared__ __align__(16) char u_lds[16 * SOFF * 4 + 16 * SATT * 4];   // 12800 B
    bf16_t* At   = (bf16_t*)u_lds;
    float*  offs = (float*)u_lds;
    float*  atts = (float*)(u_lds + 16 * SOFF * 4);
    __shared__ int rowpos[16];
    __shared__ float rref[16][2];

    // bijective XCD chunk swizzle: 1500 blocks = 8 XCDs, q=187 r=4
    const int orig = blockIdx.x;
    const int xcd = orig & 7, idx8 = orig >> 3;
    const int lb = (xcd < 4 ? xcd * 188 : 4 * 188 + (xcd - 4) * 187) + idx8;
    const int m0 = lb * 16;
    const int cam = m0 / NQ_;

    if (threadIdx.x < 16) {
        int m = m0 + threadIdx.x;
        float gx = qgrid[m * 2 + 0], gy = qgrid[m * 2 + 1];
        float fx = rintf(__fmul_rn(__fmul_rn(__fadd_rn(gx, 1.0f), 0.5f), 99.0f));
        float fy = rintf(__fmul_rn(__fmul_rn(__fadd_rn(gy, 1.0f), 0.5f), 99.0f));
        bool valid = (fx >= 0.0f) && (fx <= 99.0f) && (fy >= 0.0f) && (fy <= 99.0f);
        rowpos[threadIdx.x] = valid ? ((int)fy * BW_ + (int)fx) : -1;
    } else if (threadIdx.x < 48) {
        int t = threadIdx.x - 16;
        rref[t >> 1][t & 1] = refp[(m0 + (t >> 1)) * 2 + (t & 1)];
    }
    __syncthreads();
    {
        int idx = threadIdx.x;
#pragma unroll
        for (int it = 0; it < 2; ++it, idx += 256) {
            int r = idx >> 5, g = idx & 31;
            int p = rowpos[r];
            bf16x8 v;
            if (p >= 0) v = *(const bf16x8*)(qsum + (size_t)p * 256 + g * 8);
            else { bf16x8 z = {}; v = z; }
            *(bf16x8*)(At + r * SA + g * 8) = v;
        }
    }
    __syncthreads();
    const int lane = threadIdx.x & 63, w = threadIdx.x >> 6;
    const int lr = lane & 15, lk = lane >> 4;
    const int wcol0 = w * 48;
    f32x4 acc[3] = {};
    {
        const bf16_t* a0 = At + lr * SA + lk * 8;
        const bf16_t* b0 = WcombT + (wcol0 + lr) * 256 + lk * 8;
#pragma unroll
        for (int ks = 0; ks < 8; ++ks) {
            bf16x8 af = *(const bf16x8*)(a0 + ks * 32);
            bf16x8 bf_[3];
#pragma unroll
            for (int n = 0; n < 3; ++n) bf_[n] = *(const bf16x8*)(b0 + n * 16 * 256 + ks * 32);
#pragma unroll
            for (int n = 0; n < 3; ++n)
                acc[n] = mfma16(af, bf_[n], acc[n]);
        }
    }
    __syncthreads();
#pragma unroll
    for (int n = 0; n < 3; ++n) {
        const int colbase = wcol0 + n * 16;
        const int col = colbase + lr;
        const int rloc = lk * 4;
        if (colbase < 128) {
            float bo = boff[col];
#pragma unroll
            for (int j = 0; j < 4; ++j)
                offs[(rloc + j) * SOFF + col] = acc[n][j] + bo;
        } else {
            float bt = batt[col - 128];
#pragma unroll
            for (int j = 0; j < 4; ++j) {
                float lg = acc[n][j] + bt;
                float mx = lg;
                mx = fmaxf(mx, __shfl_xor(mx, 1, 64));
                mx = fmaxf(mx, __shfl_xor(mx, 2, 64));
                mx = fmaxf(mx, __shfl_xor(mx, 4, 64));
                float e = expf(lg - mx);
                float s = e;
                s += __shfl_xor(s, 1, 64);
                s += __shfl_xor(s, 2, 64);
                s += __shfl_xor(s, 4, 64);
                atts[(rloc + j) * SATT + (col - 128)] = e / s;
            }
        }
    }
    __syncthreads();
    // ---- phase 2: 8-lane units, 4 passes ----
    const int lane8 = threadIdx.x & 7;   // 16B chunk within the 128B x-pair
    const int jj    = lane8 & 3;         // channel octet
    const int xsel  = lane8 >> 2;        // 0 = x0 texel, 1 = x1 texel
    const int uu    = threadIdx.x >> 3;  // 0..31: unit within pass
#pragma unroll
    for (int pass = 0; pass < 4; ++pass) {
        const int unit = pass * 32 + uu;
        const int r = unit >> 3, h = unit & 7;
        const bf16_t* bhead = vh + (size_t)(cam * HEADS_ + h) * HWV * HD_;
        const float rx = rref[r][0], ry = rref[r][1];
        const float4* off4 = (const float4*)(offs + r * SOFF + h * 16);
        float offv[16];
#pragma unroll
        for (int q = 0; q < 4; ++q) {
            float4 a = off4[q];
            offv[q * 4 + 0] = a.x; offv[q * 4 + 1] = a.y;
            offv[q * 4 + 2] = a.z; offv[q * 4 + 3] = a.w;
        }
        const float* attp = atts + r * SATT + h * 8;
        float acc2[8] = {};
#pragma unroll
        for (int p = 0; p < PTS_; ++p) {
            float ax = fmaf(rx, (float)WF_, offv[p * 2 + 0] - 0.5f);
            float ay = fmaf(ry, (float)HF_, offv[p * 2 + 1] - 0.5f);
            float x0f = floorf(ax), y0f = floorf(ay);
            float wx = ax - x0f, wy = ay - y0f;
            float att = attp[p];
            bool vx0 = (x0f >= 0.0f) && (x0f <= (float)(WF_ - 1));
            bool vx1 = (x0f >= -1.0f) && (x0f <= (float)(WF_ - 2));
            bool vy0 = (y0f >= 0.0f) && (y0f <= (float)(HF_ - 1));
            bool vy1 = (y0f >= -1.0f) && (y0f <= (float)(HF_ - 2));
            float aw00 = (vx0 && vy0) ? att * (1.0f - wx) * (1.0f - wy) : 0.0f;
            float aw01 = (vx1 && vy0) ? att * wx * (1.0f - wy) : 0.0f;
            float aw10 = (vx0 && vy1) ? att * (1.0f - wx) * wy : 0.0f;
            float aw11 = (vx1 && vy1) ? att * wx * wy : 0.0f;
            // parity remap: this lane's weight for its texel slot (xsel) per y-row
            bool px = (x0f >= 0.0f);
            float wy0 = xsel ? (px ? aw01 : 0.0f) : (px ? aw00 : aw01);
            float wy1 = xsel ? (px ? aw11 : 0.0f) : (px ? aw10 : aw11);
            int xs = (int)fminf(fmaxf(x0f, 0.0f), (float)(WF_ - 1));
            int par = xs & 1;
            int tb = xs - par;
            int y0 = (int)fminf(fmaxf(y0f, 0.0f), (float)(HF_ - 1));
            int y1 = (int)fminf(fmaxf(y0f + 1.0f, 0.0f), (float)(HF_ - 1));
            const bf16_t* bp = bhead + (size_t)par * VHSHIFT;
            bf16x8 e0 = *(const bf16x8*)(bp + (y0 * WF_ + tb) * HD_ + lane8 * 8);
            bf16x8 e1 = *(const bf16x8*)(bp + (y1 * WF_ + tb) * HD_ + lane8 * 8);
#pragma unroll
            for (int c = 0; c < 8; ++c)
                acc2[c] = fmaf(wy0, (float)e0[c], fmaf(wy1, (float)e1[c], acc2[c]));
        }
        // combine x0/x1 partials across the lane^4 pair, lanes 0-3 store
        bf16x8 ov;
#pragma unroll
        for (int c = 0; c < 8; ++c) {
            float tot = acc2[c] + __shfl_xor(acc2[c], 4, 64);
            ov[c] = (bf16_t)tot;
        }
        if (xsel == 0)
            *(bf16x8*)(out_attn + (size_t)(m0 + r) * CDIM + h * HD_ + jj * 8) = ov;
    }
}

// K4: restore-BEV nearest gather (2 overlaps summed) * counts -> MFMA GEMM vs WoutT
//     + bout + residual. 32-row tiles.
__global__ __launch_bounds__(256) void k4_restore(const bf16_t* __restrict__ out_attn,
                                                  const float* __restrict__ rgrid,
                                                  const float* __restrict__ counts,
                                                  const bf16_t* __restrict__ WoutT,
                                                  const float* __restrict__ bout,
                                                  const float* __restrict__ query,
                                                  float* __restrict__ out) {
    __shared__ __align__(16) bf16_t At[32 * SA];
    __shared__ int pos2[32][2];
    __shared__ float cnt[32];
    const int m0 = blockIdx.x * 32;
    if (threadIdx.x < 64) {
        int r = threadIdx.x >> 1, k = threadIdx.x & 1;
        int i = m0 + r;
        if (i < NOUT_) {
            int bh = i / 100, bw = i - bh * 100;
            int R = bh + k * BH_;
            float gx = rgrid[(R * 100 + bw) * 2 + 0], gy = rgrid[(R * 100 + bw) * 2 + 1];
            float fx = rintf(__fmul_rn(__fmul_rn(__fadd_rn(gx, 1.0f), 0.5f), 39.0f));
            float fy = rintf(__fmul_rn(__fmul_rn(__fadd_rn(gy, 1.0f), 0.5f), 599.0f));
            bool valid = (fx >= 0.0f) && (fx <= 39.0f) && (fy >= 0.0f) && (fy <= 599.0f);
            int ix = (int)fx, iy = (int)fy;
            int camr = iy / 100, hg = iy - camr * 100;
            pos2[r][k] = valid ? (camr * NQ_ + hg * 40 + ix) : -1;
            if (k == 0) cnt[r] = counts[i];
        } else {
            pos2[r][k] = -1;
            if (k == 0) cnt[r] = 0.0f;
        }
    }
    __syncthreads();
    for (int idx = threadIdx.x; idx < 32 * 32; idx += 256) {
        int r = idx >> 5, g = idx & 31;
        int p0 = pos2[r][0], p1 = pos2[r][1];
        float s[8] = {};
        if (p0 >= 0) {
            bf16x8 a = *(const bf16x8*)(out_attn + (size_t)p0 * CDIM + g * 8);
#pragma unroll
            for (int c = 0; c < 8; ++c) s[c] += (float)a[c];
        }
        if (p1 >= 0) {
            bf16x8 a = *(const bf16x8*)(out_attn + (size_t)p1 * CDIM + g * 8);
#pragma unroll
            for (int c = 0; c < 8; ++c) s[c] += (float)a[c];
        }
        float cn = cnt[r];
        bf16x8 pk;
#pragma unroll
        for (int c = 0; c < 8; ++c) pk[c] = (bf16_t)(s[c] * cn);
        *(bf16x8*)(At + r * SA + g * 8) = pk;
    }
    __syncthreads();
    const int lane = threadIdx.x & 63, w = threadIdx.x >> 6;
    const int lr = lane & 15, lk = lane >> 4;
    f32x4 acc[2][4] = {};
    const bf16_t* a0 = At + lr * SA + lk * 8;
    const bf16_t* b0 = WoutT + (w * 64 + lr) * 256 + lk * 8;
#pragma unroll
    for (int ks = 0; ks < 8; ++ks) {
        bf16x8 af[2], bf_[4];
#pragma unroll
        for (int mm = 0; mm < 2; ++mm) af[mm] = *(const bf16x8*)(a0 + mm * 16 * SA + ks * 32);
#pragma unroll
        for (int n = 0; n < 4; ++n) bf_[n] = *(const bf16x8*)(b0 + n * 16 * 256 + ks * 32);
#pragma unroll
        for (int mm = 0; mm < 2; ++mm)
#pragma unroll
            for (int n = 0; n < 4; ++n)
                acc[mm][n] = mfma16(af[mm], bf_[n], acc[mm][n]);
    }
#pragma unroll
    for (int n = 0; n < 4; ++n) {
        int col = w * 64 + n * 16 + lr;
        float bo = bout[col];
#pragma unroll
        for (int mm = 0; mm < 2; ++mm)
#pragma unroll
            for (int j = 0; j < 4; ++j) {
                int row = m0 + mm * 16 + lk * 4 + j;
                if (row < NOUT_)
                    out[row * CDIM + col] = acc[mm][n][j] + bo + query[row * CDIM + col];
            }
    }
}

extern "C" void kernel_launch(void* const* d_in, const int* in_sizes, int n_in,
                              void* d_out, int out_size, void* d_ws, size_t ws_size,
                              hipStream_t stream) {
    (void)in_sizes; (void)n_in; (void)out_size; (void)ws_size;
    const float* query  = (const float*)d_in[0];
    const float* value  = (const float*)d_in[1];
    const float* qgrid  = (const float*)d_in[2];
    const float* rgrid  = (const float*)d_in[3];
    const float* refp   = (const float*)d_in[4];
    const float* counts = (const float*)d_in[5];
    const float* qpos   = (const float*)d_in[6];
    const float* Wv     = (const float*)d_in[7];
    const float* bv     = (const float*)d_in[8];
    const float* Woff   = (const float*)d_in[9];
    const float* boff   = (const float*)d_in[10];
    const float* Watt   = (const float*)d_in[11];
    const float* batt   = (const float*)d_in[12];
    const float* Wout   = (const float*)d_in[13];
    const float* bout   = (const float*)d_in[14];
    float* out = (float*)d_out;
    char* w8 = (char*)d_ws;

    bf16_t* vh       = (bf16_t*)(w8);                // vhE + vhO: 2 x 11,796,480 B
    bf16_t* out_attn = (bf16_t*)(w8 + 23592960);     // 12,288,000 B
    bf16_t* WvT      = (bf16_t*)(w8 + 35880960);
    bf16_t* WcombT   = (bf16_t*)(w8 + 36012032);
    bf16_t* WoutT    = (bf16_t*)(w8 + 36110336);
    bf16_t* qsum     = (bf16_t*)(w8 + 36241408);     // 5,120,000 B (end 41,361,408)

    hipLaunchKernelGGL(k0_prep,   dim3(3204),     dim3(256), 0, stream, Wv, Woff, Watt, Wout,
                       query, qpos, WvT, WcombT, WoutT, qsum);
    hipLaunchKernelGGL(k1_vproj,  dim3(M1_ / 32), dim3(256), 0, stream, value, WvT, bv, vh);
    hipLaunchKernelGGL(k23_offatt_sample, dim3(M2_ / 16), dim3(256), 0, stream,
                       qsum, qgrid, WcombT, boff, batt, refp, vh, out_attn);
    hipLaunchKernelGGL(k4_restore, dim3(313),     dim3(256), 0, stream, out_attn, rgrid, counts,
                       WoutT, bout, query, out);
}

// Round 13
// 90.330 us; speedup vs baseline: 1.0819x; 1.0819x over previous
//
#include <hip/hip_runtime.h>
#include <hip/hip_bf16.h>
#include <math.h>

// ---- problem constants ----
#define NCAMS 6
#define BH_ 100
#define BW_ 100
#define CDIM 256
#define NQ_ 4000           // HG*WG = 100*40
#define HF_ 48
#define WF_ 80
#define HEADS_ 8
#define PTS_ 8
#define HD_ 32
#define HWV (HF_*WF_)      // 3840
#define M1_ (NCAMS*HWV)    // 23040
#define M2_ (NCAMS*NQ_)    // 24000
#define NOUT_ 10000        // BH*BW
#define VHBYTES 5898240    // one fp8 vh copy: 48 slices x 3840 texels x 32 B

#define SA 264             // padded LDS tile row stride in bf16 elems
#define SOFF 132           // padded off row stride (floats)
#define SATT 68            // padded att row stride (floats)

typedef __bf16 bf16_t;
typedef __bf16 bf16x8 __attribute__((ext_vector_type(8)));
typedef __bf16 bf16x4 __attribute__((ext_vector_type(4)));
typedef float  f32x4  __attribute__((ext_vector_type(4)));
typedef float  f32x2  __attribute__((ext_vector_type(2)));

static __device__ __forceinline__ f32x4 mfma16(bf16x8 a, bf16x8 b, f32x4 c) {
    return __builtin_amdgcn_mfma_f32_16x16x32_bf16(a, b, c, 0, 0, 0);
}

// K0: bf16 transposed weights + qsum = (bf16)(query + query_pos).
__global__ __launch_bounds__(256) void k0_prep(const float* __restrict__ Wv,
                                               const float* __restrict__ Woff,
                                               const float* __restrict__ Watt,
                                               const float* __restrict__ Wout,
                                               const float* __restrict__ query,
                                               const float* __restrict__ qpos,
                                               bf16_t* __restrict__ WvT,
                                               bf16_t* __restrict__ WcombT,
                                               bf16_t* __restrict__ WoutT,
                                               bf16_t* __restrict__ qsum) {
    int b = blockIdx.x, k = threadIdx.x;
    if (b < 256) {
        WvT[b * 256 + k] = (bf16_t)Wv[k * 256 + b];
    } else if (b < 448) {
        int n = b - 256;
        float v = (n < 128) ? Woff[k * 128 + n] : Watt[k * 64 + (n - 128)];
        WcombT[n * 256 + k] = (bf16_t)v;
    } else if (b < 704) {
        int n = b - 448;
        WoutT[n * 256 + k] = (bf16_t)Wout[k * 256 + n];
    } else {
        int row0 = (b - 704) * 4;                 // 4 rows per block
        int r = k >> 6, c4 = k & 63;
        int i = (row0 + r) * 64 + c4;             // float4 index
        float4 a = ((const float4*)query)[i];
        float4 p = ((const float4*)qpos)[i];
        bf16x4 pk;
        pk[0] = (bf16_t)(a.x + p.x); pk[1] = (bf16_t)(a.y + p.y);
        pk[2] = (bf16_t)(a.z + p.z); pk[3] = (bf16_t)(a.w + p.w);
        *(bf16x4*)(qsum + (size_t)i * 4) = pk;
    }
}

// K1: value @ Wv + bv -> vh in FP8 e4m3, 32 B texels, dual-parity copies:
// vhE linear, vhO shift-by-one-texel (tail dup) -> any x-pair = one 64B-aligned line.
__global__ __launch_bounds__(256) void k1_vproj(const float* __restrict__ value,
                                                const bf16_t* __restrict__ WvT,
                                                const float* __restrict__ bv,
                                                unsigned char* __restrict__ vh8) {
    __shared__ __align__(16) bf16_t At[32 * SA];
    const int m0 = blockIdx.x * 32;
    const int cam = m0 / HWV;
    const int hw0 = m0 - cam * HWV;
    for (int idx = threadIdx.x; idx < 32 * 64; idx += 256) {
        int r = idx >> 6, c4 = idx & 63;
        float4 v = ((const float4*)value)[((hw0 + r) * NCAMS + cam) * 64 + c4];
        bf16x4 pk; pk[0] = (bf16_t)v.x; pk[1] = (bf16_t)v.y; pk[2] = (bf16_t)v.z; pk[3] = (bf16_t)v.w;
        *(bf16x4*)(At + r * SA + c4 * 4) = pk;
    }
    __syncthreads();
    const int lane = threadIdx.x & 63, w = threadIdx.x >> 6;
    const int lr = lane & 15, lk = lane >> 4;
    f32x4 acc[2][4] = {};
    const bf16_t* a0 = At + lr * SA + lk * 8;
    const bf16_t* b0 = WvT + (w * 64 + lr) * 256 + lk * 8;
#pragma unroll
    for (int ks = 0; ks < 8; ++ks) {
        bf16x8 af[2], bf_[4];
#pragma unroll
        for (int mm = 0; mm < 2; ++mm) af[mm] = *(const bf16x8*)(a0 + mm * 16 * SA + ks * 32);
#pragma unroll
        for (int n = 0; n < 4; ++n) bf_[n] = *(const bf16x8*)(b0 + n * 16 * 256 + ks * 32);
#pragma unroll
        for (int mm = 0; mm < 2; ++mm)
#pragma unroll
            for (int n = 0; n < 4; ++n)
                acc[mm][n] = mfma16(af[mm], bf_[n], acc[mm][n]);
    }
    __syncthreads();
#pragma unroll
    for (int n = 0; n < 4; ++n) {
        int col = w * 64 + n * 16 + lr;
        float bias = bv[col];
#pragma unroll
        for (int mm = 0; mm < 2; ++mm)
#pragma unroll
            for (int j = 0; j < 4; ++j)
                At[(mm * 16 + lk * 4 + j) * SA + col] = (bf16_t)(acc[mm][n][j] + bias);
    }
    __syncthreads();
    // stores: 32 rows x 32 octets; each octet -> 8 fp8 (8 B)
    for (int idx = threadIdx.x; idx < 32 * 32; idx += 256) {
        int r = idx >> 5, g = idx & 31;
        int head = g >> 2, part = g & 3;
        bf16x8 v = *(const bf16x8*)(At + r * SA + g * 8);
        int d0 = 0, d1 = 0;
        d0 = __builtin_amdgcn_cvt_pk_fp8_f32((float)v[0], (float)v[1], d0, false);
        d0 = __builtin_amdgcn_cvt_pk_fp8_f32((float)v[2], (float)v[3], d0, true);
        d1 = __builtin_amdgcn_cvt_pk_fp8_f32((float)v[4], (float)v[5], d1, false);
        d1 = __builtin_amdgcn_cvt_pk_fp8_f32((float)v[6], (float)v[7], d1, true);
        int2 pk8 = make_int2(d0, d1);
        int hw = hw0 + r;
        int y = hw / WF_;
        int x = hw - y * WF_;
        size_t rowbase = (size_t)(cam * HEADS_ + head) * 122880 + (size_t)y * (WF_ * 32);
        int o = x * 32 + part * 8;
        *(int2*)(vh8 + rowbase + o) = pk8;                              // vhE
        if (o >= 32) *(int2*)(vh8 + VHBYTES + rowbase + o - 32) = pk8;  // vhO main
        if (x == WF_ - 1) *(int2*)(vh8 + VHBYTES + rowbase + o) = pk8;  // vhO tail dup
    }
}

// K23: fused offsets/attention GEMM + bilinear deformable sampling on FP8 vh.
// Phase 2: 4-lane units; lane = (xsel,chhalf). The unit's x-pair is ONE 64 B
// line (parity-selected copy) -> 2 transactions per unit-point. Dequant via
// v_cvt_pk_f32_fp8. Two interleaved units per thread (rows r0, r0+8).
__global__ __launch_bounds__(256) void k23_offatt_sample(
        const bf16_t* __restrict__ qsum,
        const float* __restrict__ qgrid,
        const bf16_t* __restrict__ WcombT,
        const float* __restrict__ boff,
        const float* __restrict__ batt,
        const float* __restrict__ refp,
        const unsigned char* __restrict__ vh8,
        bf16_t* __restrict__ out_attn) {
    __shared__ __align__(16) char u_lds[16 * SOFF * 4 + 16 * SATT * 4];   // 12800 B
    bf16_t* At   = (bf16_t*)u_lds;
    float*  offs = (float*)u_lds;
    float*  atts = (float*)(u_lds + 16 * SOFF * 4);
    __shared__ int rowpos[16];
    __shared__ float rref[16][2];

    // bijective XCD chunk swizzle: 1500 blocks = 8 XCDs, q=187 r=4
    const int orig = blockIdx.x;
    const int xcd = orig & 7, idx8 = orig >> 3;
    const int lb = (xcd < 4 ? xcd * 188 : 4 * 188 + (xcd - 4) * 187) + idx8;
    const int m0 = lb * 16;
    const int cam = m0 / NQ_;

    if (threadIdx.x < 16) {
        int m = m0 + threadIdx.x;
        float gx = qgrid[m * 2 + 0], gy = qgrid[m * 2 + 1];
        float fx = rintf(__fmul_rn(__fmul_rn(__fadd_rn(gx, 1.0f), 0.5f), 99.0f));
        float fy = rintf(__fmul_rn(__fmul_rn(__fadd_rn(gy, 1.0f), 0.5f), 99.0f));
        bool valid = (fx >= 0.0f) && (fx <= 99.0f) && (fy >= 0.0f) && (fy <= 99.0f);
        rowpos[threadIdx.x] = valid ? ((int)fy * BW_ + (int)fx) : -1;
    } else if (threadIdx.x < 48) {
        int t = threadIdx.x - 16;
        rref[t >> 1][t & 1] = refp[(m0 + (t >> 1)) * 2 + (t & 1)];
    }
    __syncthreads();
    {
        int idx = threadIdx.x;
#pragma unroll
        for (int it = 0; it < 2; ++it, idx += 256) {
            int r = idx >> 5, g = idx & 31;
            int p = rowpos[r];
            bf16x8 v;
            if (p >= 0) v = *(const bf16x8*)(qsum + (size_t)p * 256 + g * 8);
            else { bf16x8 z = {}; v = z; }
            *(bf16x8*)(At + r * SA + g * 8) = v;
        }
    }
    __syncthreads();
    const int lane = threadIdx.x & 63, w = threadIdx.x >> 6;
    const int lr = lane & 15, lk = lane >> 4;
    const int wcol0 = w * 48;
    f32x4 acc[3] = {};
    {
        const bf16_t* a0 = At + lr * SA + lk * 8;
        const bf16_t* b0 = WcombT + (wcol0 + lr) * 256 + lk * 8;
#pragma unroll
        for (int ks = 0; ks < 8; ++ks) {
            bf16x8 af = *(const bf16x8*)(a0 + ks * 32);
            bf16x8 bf_[3];
#pragma unroll
            for (int n = 0; n < 3; ++n) bf_[n] = *(const bf16x8*)(b0 + n * 16 * 256 + ks * 32);
#pragma unroll
            for (int n = 0; n < 3; ++n)
                acc[n] = mfma16(af, bf_[n], acc[n]);
        }
    }
    __syncthreads();
#pragma unroll
    for (int n = 0; n < 3; ++n) {
        const int colbase = wcol0 + n * 16;
        const int col = colbase + lr;
        const int rloc = lk * 4;
        if (colbase < 128) {
            float bo = boff[col];
#pragma unroll
            for (int j = 0; j < 4; ++j)
                offs[(rloc + j) * SOFF + col] = acc[n][j] + bo;
        } else {
            float bt = batt[col - 128];
#pragma unroll
            for (int j = 0; j < 4; ++j) {
                float lg = acc[n][j] + bt;
                float mx = lg;
                mx = fmaxf(mx, __shfl_xor(mx, 1, 64));
                mx = fmaxf(mx, __shfl_xor(mx, 2, 64));
                mx = fmaxf(mx, __shfl_xor(mx, 4, 64));
                float e = expf(lg - mx);
                float s = e;
                s += __shfl_xor(s, 1, 64);
                s += __shfl_xor(s, 2, 64);
                s += __shfl_xor(s, 4, 64);
                atts[(rloc + j) * SATT + (col - 128)] = e / s;
            }
        }
    }
    __syncthreads();
    // ---- phase 2: 4-lane units; lane = (xsel<<1)|chhalf within the unit ----
    const int chh  = threadIdx.x & 1;              // 0: ch0-15, 1: ch16-31
    const int xsel = (threadIdx.x >> 1) & 1;       // 0: x0 texel, 1: x1 texel
    const int lanoff = (threadIdx.x & 3) * 16;     // byte chunk within 64B pair
    const int u0 = threadIdx.x >> 2;               // 0..63
    const int r0 = u0 >> 3, h = u0 & 7, r1 = r0 + 8;
    const unsigned char* bslice = vh8 + (size_t)(cam * HEADS_ + h) * 122880;
    const float rxA = rref[r0][0], ryA = rref[r0][1];
    const float rxB = rref[r1][0], ryB = rref[r1][1];
    const float4* offA4 = (const float4*)(offs + r0 * SOFF + h * 16);
    const float4* offB4 = (const float4*)(offs + r1 * SOFF + h * 16);
    float oA[16], oB[16];
#pragma unroll
    for (int q = 0; q < 4; ++q) {
        float4 a = offA4[q], b = offB4[q];
        oA[q * 4 + 0] = a.x; oA[q * 4 + 1] = a.y; oA[q * 4 + 2] = a.z; oA[q * 4 + 3] = a.w;
        oB[q * 4 + 0] = b.x; oB[q * 4 + 1] = b.y; oB[q * 4 + 2] = b.z; oB[q * 4 + 3] = b.w;
    }
    const float* attA = atts + r0 * SATT + h * 8;
    const float* attB = atts + r1 * SATT + h * 8;
    float accA[16] = {}, accB[16] = {};
#pragma unroll
    for (int p = 0; p < PTS_; ++p) {
        // ---- unit A coords/weights ----
        float axA = fmaf(rxA, (float)WF_, oA[p * 2 + 0] - 0.5f);
        float ayA = fmaf(ryA, (float)HF_, oA[p * 2 + 1] - 0.5f);
        float xA0f = floorf(axA), yA0f = floorf(ayA);
        float wxA = axA - xA0f, wyA = ayA - yA0f;
        float attA_p = attA[p];
        bool vxA0 = (xA0f >= 0.0f) && (xA0f <= (float)(WF_ - 1));
        bool vxA1 = (xA0f >= -1.0f) && (xA0f <= (float)(WF_ - 2));
        bool vyA0 = (yA0f >= 0.0f) && (yA0f <= (float)(HF_ - 1));
        bool vyA1 = (yA0f >= -1.0f) && (yA0f <= (float)(HF_ - 2));
        float awA00 = (vxA0 && vyA0) ? attA_p * (1.0f - wxA) * (1.0f - wyA) : 0.0f;
        float awA01 = (vxA1 && vyA0) ? attA_p * wxA * (1.0f - wyA) : 0.0f;
        float awA10 = (vxA0 && vyA1) ? attA_p * (1.0f - wxA) * wyA : 0.0f;
        float awA11 = (vxA1 && vyA1) ? attA_p * wxA * wyA : 0.0f;
        bool pxA = (xA0f >= 0.0f);
        float wqA0 = xsel ? (pxA ? awA01 : 0.0f) : (pxA ? awA00 : awA01);  // y0 row
        float wqA1 = xsel ? (pxA ? awA11 : 0.0f) : (pxA ? awA10 : awA11);  // y1 row
        int xsA = (int)fminf(fmaxf(xA0f, 0.0f), (float)(WF_ - 1));
        int parA = xsA & 1;
        int tbA = xsA - parA;
        int yA0 = (int)fminf(fmaxf(yA0f, 0.0f), (float)(HF_ - 1));
        int yA1 = (int)fminf(fmaxf(yA0f + 1.0f, 0.0f), (float)(HF_ - 1));
        const unsigned char* bpA = bslice + (size_t)parA * VHBYTES;
        // ---- unit B coords/weights ----
        float axB = fmaf(rxB, (float)WF_, oB[p * 2 + 0] - 0.5f);
        float ayB = fmaf(ryB, (float)HF_, oB[p * 2 + 1] - 0.5f);
        float xB0f = floorf(axB), yB0f = floorf(ayB);
        float wxB = axB - xB0f, wyB = ayB - yB0f;
        float attB_p = attB[p];
        bool vxB0 = (xB0f >= 0.0f) && (xB0f <= (float)(WF_ - 1));
        bool vxB1 = (xB0f >= -1.0f) && (xB0f <= (float)(WF_ - 2));
        bool vyB0 = (yB0f >= 0.0f) && (yB0f <= (float)(HF_ - 1));
        bool vyB1 = (yB0f >= -1.0f) && (yB0f <= (float)(HF_ - 2));
        float awB00 = (vxB0 && vyB0) ? attB_p * (1.0f - wxB) * (1.0f - wyB) : 0.0f;
        float awB01 = (vxB1 && vyB0) ? attB_p * wxB * (1.0f - wyB) : 0.0f;
        float awB10 = (vxB0 && vyB1) ? attB_p * (1.0f - wxB) * wyB : 0.0f;
        float awB11 = (vxB1 && vyB1) ? attB_p * wxB * wyB : 0.0f;
        bool pxB = (xB0f >= 0.0f);
        float wqB0 = xsel ? (pxB ? awB01 : 0.0f) : (pxB ? awB00 : awB01);
        float wqB1 = xsel ? (pxB ? awB11 : 0.0f) : (pxB ? awB10 : awB11);
        int xsB = (int)fminf(fmaxf(xB0f, 0.0f), (float)(WF_ - 1));
        int parB = xsB & 1;
        int tbB = xsB - parB;
        int yB0 = (int)fminf(fmaxf(yB0f, 0.0f), (float)(HF_ - 1));
        int yB1 = (int)fminf(fmaxf(yB0f + 1.0f, 0.0f), (float)(HF_ - 1));
        const unsigned char* bpB = bslice + (size_t)parB * VHBYTES;
        // ---- 4 coalesced 64B-line loads in flight ----
        int4 qA0 = *(const int4*)(bpA + (yA0 * WF_ + tbA) * 32 + lanoff);
        int4 qA1 = *(const int4*)(bpA + (yA1 * WF_ + tbA) * 32 + lanoff);
        int4 qB0 = *(const int4*)(bpB + (yB0 * WF_ + tbB) * 32 + lanoff);
        int4 qB1 = *(const int4*)(bpB + (yB1 * WF_ + tbB) * 32 + lanoff);
        // dequant + accumulate (16 channels per lane)
        int dA0[4] = {qA0.x, qA0.y, qA0.z, qA0.w};
        int dA1[4] = {qA1.x, qA1.y, qA1.z, qA1.w};
        int dB0[4] = {qB0.x, qB0.y, qB0.z, qB0.w};
        int dB1[4] = {qB1.x, qB1.y, qB1.z, qB1.w};
#pragma unroll
        for (int kq = 0; kq < 4; ++kq) {
            f32x2 lo, hi;
            lo = __builtin_amdgcn_cvt_pk_f32_fp8(dA0[kq], false);
            hi = __builtin_amdgcn_cvt_pk_f32_fp8(dA0[kq], true);
            accA[kq * 4 + 0] = fmaf(wqA0, lo[0], accA[kq * 4 + 0]);
            accA[kq * 4 + 1] = fmaf(wqA0, lo[1], accA[kq * 4 + 1]);
            accA[kq * 4 + 2] = fmaf(wqA0, hi[0], accA[kq * 4 + 2]);
            accA[kq * 4 + 3] = fmaf(wqA0, hi[1], accA[kq * 4 + 3]);
            lo = __builtin_amdgcn_cvt_pk_f32_fp8(dA1[kq], false);
            hi = __builtin_amdgcn_cvt_pk_f32_fp8(dA1[kq], true);
            accA[kq * 4 + 0] = fmaf(wqA1, lo[0], accA[kq * 4 + 0]);
            accA[kq * 4 + 1] = fmaf(wqA1, lo[1], accA[kq * 4 + 1]);
            accA[kq * 4 + 2] = fmaf(wqA1, hi[0], accA[kq * 4 + 2]);
            accA[kq * 4 + 3] = fmaf(wqA1, hi[1], accA[kq * 4 + 3]);
            lo = __builtin_amdgcn_cvt_pk_f32_fp8(dB0[kq], false);
            hi = __builtin_amdgcn_cvt_pk_f32_fp8(dB0[kq], true);
            accB[kq * 4 + 0] = fmaf(wqB0, lo[0], accB[kq * 4 + 0]);
            accB[kq * 4 + 1] = fmaf(wqB0, lo[1], accB[kq * 4 + 1]);
            accB[kq * 4 + 2] = fmaf(wqB0, hi[0], accB[kq * 4 + 2]);
            accB[kq * 4 + 3] = fmaf(wqB0, hi[1], accB[kq * 4 + 3]);
            lo = __builtin_amdgcn_cvt_pk_f32_fp8(dB1[kq], false);
            hi = __builtin_amdgcn_cvt_pk_f32_fp8(dB1[kq], true);
            accB[kq * 4 + 0] = fmaf(wqB1, lo[0], accB[kq * 4 + 0]);
            accB[kq * 4 + 1] = fmaf(wqB1, lo[1], accB[kq * 4 + 1]);
            accB[kq * 4 + 2] = fmaf(wqB1, hi[0], accB[kq * 4 + 2]);
            accB[kq * 4 + 3] = fmaf(wqB1, hi[1], accB[kq * 4 + 3]);
        }
    }
    // combine x0/x1 partials across lane^2; lanes with xsel==0 store 16 chans
#pragma unroll
    for (int c = 0; c < 16; ++c) {
        accA[c] += __shfl_xor(accA[c], 2, 64);
        accB[c] += __shfl_xor(accB[c], 2, 64);
    }
    if (xsel == 0) {
        bf16x8 a0v, a1v, b0v, b1v;
#pragma unroll
        for (int c = 0; c < 8; ++c) {
            a0v[c] = (bf16_t)accA[c]; a1v[c] = (bf16_t)accA[c + 8];
            b0v[c] = (bf16_t)accB[c]; b1v[c] = (bf16_t)accB[c + 8];
        }
        bf16_t* dA = out_attn + (size_t)(m0 + r0) * CDIM + h * HD_ + chh * 16;
        bf16_t* dB = out_attn + (size_t)(m0 + r1) * CDIM + h * HD_ + chh * 16;
        *(bf16x8*)(dA) = a0v; *(bf16x8*)(dA + 8) = a1v;
        *(bf16x8*)(dB) = b0v; *(bf16x8*)(dB + 8) = b1v;
    }
}

// K4: restore-BEV nearest gather (2 overlaps summed) * counts -> MFMA GEMM vs WoutT
//     + bout + residual. 32-row tiles.
__global__ __launch_bounds__(256) void k4_restore(const bf16_t* __restrict__ out_attn,
                                                  const float* __restrict__ rgrid,
                                                  const float* __restrict__ counts,
                                                  const bf16_t* __restrict__ WoutT,
                                                  const float* __restrict__ bout,
                                                  const float* __restrict__ query,
                                                  float* __restrict__ out) {
    __shared__ __align__(16) bf16_t At[32 * SA];
    __shared__ int pos2[32][2];
    __shared__ float cnt[32];
    const int m0 = blockIdx.x * 32;
    if (threadIdx.x < 64) {
        int r = threadIdx.x >> 1, k = threadIdx.x & 1;
        int i = m0 + r;
        if (i < NOUT_) {
            int bh = i / 100, bw = i - bh * 100;
            int R = bh + k * BH_;
            float gx = rgrid[(R * 100 + bw) * 2 + 0], gy = rgrid[(R * 100 + bw) * 2 + 1];
            float fx = rintf(__fmul_rn(__fmul_rn(__fadd_rn(gx, 1.0f), 0.5f), 39.0f));
            float fy = rintf(__fmul_rn(__fmul_rn(__fadd_rn(gy, 1.0f), 0.5f), 599.0f));
            bool valid = (fx >= 0.0f) && (fx <= 39.0f) && (fy >= 0.0f) && (fy <= 599.0f);
            int ix = (int)fx, iy = (int)fy;
            int camr = iy / 100, hg = iy - camr * 100;
            pos2[r][k] = valid ? (camr * NQ_ + hg * 40 + ix) : -1;
            if (k == 0) cnt[r] = counts[i];
        } else {
            pos2[r][k] = -1;
            if (k == 0) cnt[r] = 0.0f;
        }
    }
    __syncthreads();
    for (int idx = threadIdx.x; idx < 32 * 32; idx += 256) {
        int r = idx >> 5, g = idx & 31;
        int p0 = pos2[r][0], p1 = pos2[r][1];
        float s[8] = {};
        if (p0 >= 0) {
            bf16x8 a = *(const bf16x8*)(out_attn + (size_t)p0 * CDIM + g * 8);
#pragma unroll
            for (int c = 0; c < 8; ++c) s[c] += (float)a[c];
        }
        if (p1 >= 0) {
            bf16x8 a = *(const bf16x8*)(out_attn + (size_t)p1 * CDIM + g * 8);
#pragma unroll
            for (int c = 0; c < 8; ++c) s[c] += (float)a[c];
        }
        float cn = cnt[r];
        bf16x8 pk;
#pragma unroll
        for (int c = 0; c < 8; ++c) pk[c] = (bf16_t)(s[c] * cn);
        *(bf16x8*)(At + r * SA + g * 8) = pk;
    }
    __syncthreads();
    const int lane = threadIdx.x & 63, w = threadIdx.x >> 6;
    const int lr = lane & 15, lk = lane >> 4;
    f32x4 acc[2][4] = {};
    const bf16_t* a0 = At + lr * SA + lk * 8;
    const bf16_t* b0 = WoutT + (w * 64 + lr) * 256 + lk * 8;
#pragma unroll
    for (int ks = 0; ks < 8; ++ks) {
        bf16x8 af[2], bf_[4];
#pragma unroll
        for (int mm = 0; mm < 2; ++mm) af[mm] = *(const bf16x8*)(a0 + mm * 16 * SA + ks * 32);
#pragma unroll
        for (int n = 0; n < 4; ++n) bf_[n] = *(const bf16x8*)(b0 + n * 16 * 256 + ks * 32);
#pragma unroll
        for (int mm = 0; mm < 2; ++mm)
#pragma unroll
            for (int n = 0; n < 4; ++n)
                acc[mm][n] = mfma16(af[mm], bf_[n], acc[mm][n]);
    }
#pragma unroll
    for (int n = 0; n < 4; ++n) {
        int col = w * 64 + n * 16 + lr;
        float bo = bout[col];
#pragma unroll
        for (int mm = 0; mm < 2; ++mm)
#pragma unroll
            for (int j = 0; j < 4; ++j) {
                int row = m0 + mm * 16 + lk * 4 + j;
                if (row < NOUT_)
                    out[row * CDIM + col] = acc[mm][n][j] + bo + query[row * CDIM + col];
            }
    }
}

extern "C" void kernel_launch(void* const* d_in, const int* in_sizes, int n_in,
                              void* d_out, int out_size, void* d_ws, size_t ws_size,
                              hipStream_t stream) {
    (void)in_sizes; (void)n_in; (void)out_size; (void)ws_size;
    const float* query  = (const float*)d_in[0];
    const float* value  = (const float*)d_in[1];
    const float* qgrid  = (const float*)d_in[2];
    const float* rgrid  = (const float*)d_in[3];
    const float* refp   = (const float*)d_in[4];
    const float* counts = (const float*)d_in[5];
    const float* qpos   = (const float*)d_in[6];
    const float* Wv     = (const float*)d_in[7];
    const float* bv     = (const float*)d_in[8];
    const float* Woff   = (const float*)d_in[9];
    const float* boff   = (const float*)d_in[10];
    const float* Watt   = (const float*)d_in[11];
    const float* batt   = (const float*)d_in[12];
    const float* Wout   = (const float*)d_in[13];
    const float* bout   = (const float*)d_in[14];
    float* out = (float*)d_out;
    char* w8 = (char*)d_ws;

    unsigned char* vh8 = (unsigned char*)(w8);       // vhE + vhO: 2 x 5,898,240 B
    bf16_t* out_attn = (bf16_t*)(w8 + 11796480);     // 12,288,000 B
    bf16_t* WvT      = (bf16_t*)(w8 + 24084480);     // 131,072 B
    bf16_t* WcombT   = (bf16_t*)(w8 + 24215552);     // 98,304 B
    bf16_t* WoutT    = (bf16_t*)(w8 + 24313856);     // 131,072 B
    bf16_t* qsum     = (bf16_t*)(w8 + 24444928);     // 5,120,000 B (end 29,564,928)

    hipLaunchKernelGGL(k0_prep,   dim3(3204),     dim3(256), 0, stream, Wv, Woff, Watt, Wout,
                       query, qpos, WvT, WcombT, WoutT, qsum);
    hipLaunchKernelGGL(k1_vproj,  dim3(M1_ / 32), dim3(256), 0, stream, value, WvT, bv, vh8);
    hipLaunchKernelGGL(k23_offatt_sample, dim3(M2_ / 16), dim3(256), 0, stream,
                       qsum, qgrid, WcombT, boff, batt, refp, vh8, out_attn);
    hipLaunchKernelGGL(k4_restore, dim3(313),     dim3(256), 0, stream, out_attn, rgrid, counts,
                       WoutT, bout, query, out);
}